// Round 2
// baseline (605.687 us; speedup 1.0000x reference)
//
#include <hip/hip_runtime.h>
#include <stdint.h>

typedef __attribute__((ext_vector_type(8))) short bf16x8;
typedef __attribute__((ext_vector_type(4))) short s16x4;
typedef __attribute__((ext_vector_type(4))) float f32x4;

#define DEV static __device__ __forceinline__

DEV short f2bf(float f) {
    union { float f; uint32_t u; } v; v.f = f;
    uint32_t r = (v.u + 0x7fffu + ((v.u >> 16) & 1u)) >> 16;
    return (short)r;
}

DEV void gll16(const void* g, void* l) {
    __builtin_amdgcn_global_load_lds(
        (const __attribute__((address_space(1))) uint32_t*)g,
        (__attribute__((address_space(3))) uint32_t*)l, 16, 0, 0);
}

DEV void wait_vm0()   { asm volatile("s_waitcnt vmcnt(0)" ::: "memory"); }
DEV void wait_lgkm0() { asm volatile("s_waitcnt lgkmcnt(0)" ::: "memory"); }

// ---------------- fp32 -> bf16 convert ----------------
__global__ __launch_bounds__(256) void k_convert(
    const float* __restrict__ x,  short* __restrict__ xb,
    const float* __restrict__ wq, short* __restrict__ wqb,
    const float* __restrict__ wo, short* __restrict__ wob)
{
    const int NX = (8192*1024)/4, NW = (3072*1024)/4, NO = (1024*1024)/4;
    const int total = NX + NW + NO;
    for (int i = blockIdx.x*blockDim.x + threadIdx.x; i < total; i += gridDim.x*blockDim.x) {
        const float* s; short* d; int j;
        if (i < NX)           { s = x;  d = xb;  j = i; }
        else if (i < NX + NW) { s = wq; d = wqb; j = i - NX; }
        else                  { s = wo; d = wob; j = i - NX - NW; }
        f32x4 v = *(const f32x4*)(s + (size_t)j*4);
        s16x4 o;
        o[0] = f2bf(v[0]); o[1] = f2bf(v[1]); o[2] = f2bf(v[2]); o[3] = f2bf(v[3]);
        *(s16x4*)(d + (size_t)j*4) = o;
    }
}

// ---------------- NT GEMM: C[m][n] = sum_k A[m][k]*Bw[n][k] + bias[n] ----------------
// MODE 0: write bf16 via LDS transpose (coalesced), MODE 1: write fp32 direct.
template<int MODE>
__global__ __launch_bounds__(256) void k_gemm(
    const short* __restrict__ A,    // [Mtot][K] bf16
    const short* __restrict__ Bw,   // [Ntot][K] bf16
    const float* __restrict__ bias, // [Ntot] fp32
    void* __restrict__ Cout,        // MODE0: bf16 [Mtot][Nld]; MODE1: fp32 [Mtot][Nld]
    int Nld, int K)
{
    __shared__ short smem[17408];       // As[8192] | Bs[8192]; epilogue C[128][136]
    short* As = smem;
    short* Bs = smem + 8192;
    const int tid = threadIdx.x;
    const int l = tid & 63, w = tid >> 6;
    const int bm = blockIdx.x << 7, bn = blockIdx.y << 7;
    const int wm = (w >> 1) << 6, wn = (w & 1) << 6;
    const int l15 = l & 15, lh = l >> 4;
    const int rS = tid >> 3, cS = tid & 7;   // staging: row chunk within 32-row round

    f32x4 acc[4][4] = {};
    const int KT = K >> 6;

    for (int kt = 0; kt < KT; ++kt) {
        const int k0 = kt << 6;
        #pragma unroll
        for (int rr = 0; rr < 4; ++rr) {
            int r = (rr << 5) + rS;
            int cs = (cS ^ (r & 7)) << 3;            // pre-swizzled global source
            gll16(A  + (size_t)(bm + r)*K + k0 + cs, As + ((rr<<8) + tid)*8);
            gll16(Bw + (size_t)(bn + r)*K + k0 + cs, Bs + ((rr<<8) + tid)*8);
        }
        wait_vm0();
        __syncthreads();

        bf16x8 af[2][4], bfr[2][4];
        #pragma unroll
        for (int ks = 0; ks < 2; ++ks) {
            #pragma unroll
            for (int mf = 0; mf < 4; ++mf) {
                int r = wm + (mf << 4) + l15;
                int cc = ((ks << 5) + (lh << 3)) ^ ((r & 7) << 3);
                af[ks][mf] = *(const bf16x8*)(As + r*64 + cc);
            }
            #pragma unroll
            for (int nf = 0; nf < 4; ++nf) {
                int r = wn + (nf << 4) + l15;
                int cc = ((ks << 5) + (lh << 3)) ^ ((r & 7) << 3);
                bfr[ks][nf] = *(const bf16x8*)(Bs + r*64 + cc);
            }
        }
        #pragma unroll
        for (int ks = 0; ks < 2; ++ks)
            #pragma unroll
            for (int mf = 0; mf < 4; ++mf)
                #pragma unroll
                for (int nf = 0; nf < 4; ++nf)
                    acc[mf][nf] = __builtin_amdgcn_mfma_f32_16x16x32_bf16(
                        af[ks][mf], bfr[ks][nf], acc[mf][nf], 0, 0, 0);
        __syncthreads();
    }

    float bv[4];
    #pragma unroll
    for (int nf = 0; nf < 4; ++nf) bv[nf] = bias[bn + wn + (nf<<4) + l15];

    if (MODE == 0) {
        #pragma unroll
        for (int mf = 0; mf < 4; ++mf)
            #pragma unroll
            for (int nf = 0; nf < 4; ++nf)
                #pragma unroll
                for (int v = 0; v < 4; ++v) {
                    int r = wm + (mf<<4) + (lh<<2) + v;
                    int c = wn + (nf<<4) + l15;
                    smem[r*136 + c] = f2bf(acc[mf][nf][v] + bv[nf]);
                }
        __syncthreads();
        int r = tid >> 1, half = tid & 1;
        const short* src = smem + r*136 + (half << 6);
        short* dst = (short*)Cout + (size_t)(bm + r)*Nld + bn + (half << 6);
        #pragma unroll
        for (int c = 0; c < 8; ++c)            // FIX: was c<4 — half the tile never stored
            *(bf16x8*)(dst + (c<<3)) = *(const bf16x8*)(src + (c<<3));
    } else {
        float* C = (float*)Cout;
        #pragma unroll
        for (int mf = 0; mf < 4; ++mf)
            #pragma unroll
            for (int nf = 0; nf < 4; ++nf)
                #pragma unroll
                for (int v = 0; v < 4; ++v) {
                    int r = bm + wm + (mf<<4) + (lh<<2) + v;
                    int c = bn + wn + (nf<<4) + l15;
                    C[(size_t)r*Nld + c] = acc[mf][nf][v] + bv[nf];
                }
    }
}

// ---------------- flash attention ----------------
// qkv: [8192][3072] bf16 rows m=b*2048+t, cols: Q h*64+d | K 1024+h*64+d | V 2048+h*64+d
// Ob : [8192][1024] bf16  (attention output, [B,T,H*DH])
__global__ __launch_bounds__(256) void k_attn(
    const short* __restrict__ qkv, short* __restrict__ Ob)
{
    __shared__ short Ks[4096];       // K tile  [64 kv][64 d]   (swizzled)
    __shared__ short Vlin[4096];     // V tile  [64 kv][64 d]   (swizzled)
    __shared__ short Vts[4096];      // V^T     [64 d][64 kv]   (swizzled)
    __shared__ short Pl[4][2048];    // per-wave P [32 q][64 kv] (swizzled)

    const int tid = threadIdx.x;
    const int l = tid & 63, w = tid >> 6;
    const int l15 = l & 15, lh = l >> 4;
    const int qt0 = blockIdx.x << 7;
    const int bh = blockIdx.y;
    const int b = bh >> 4, h = bh & 15;
    const short* Qbase = qkv + (size_t)(b << 11) * 3072 + (h << 6);
    const short* Kbase = Qbase + 1024;
    const short* Vbase = Qbase + 2048;
    short* Plw = &Pl[w][0];
    const int rS = tid >> 3, cS = tid & 7;

    // Q fragments in registers for the whole block lifetime
    bf16x8 qfr[2][2];
    #pragma unroll
    for (int qf = 0; qf < 2; ++qf)
        #pragma unroll
        for (int ks = 0; ks < 2; ++ks) {
            int t = qt0 + (w << 5) + (qf << 4) + l15;
            qfr[qf][ks] = *(const bf16x8*)(Qbase + (size_t)t*3072 + (ks << 5) + (lh << 3));
        }

    f32x4 o[2][4] = {};
    float mr[2][4], sr[2][4];
    #pragma unroll
    for (int qf = 0; qf < 2; ++qf)
        #pragma unroll
        for (int v = 0; v < 4; ++v) { mr[qf][v] = -__builtin_inff(); sr[qf][v] = 0.f; }
    const float SCALE = 0.125f * 1.44269504088896341f;   // (1/sqrt(64)) * log2(e)

    auto stage = [&](int kv0) {
        #pragma unroll
        for (int rr = 0; rr < 2; ++rr) {
            int r = (rr << 5) + rS;
            int cs = (cS ^ (r & 7)) << 3;
            size_t grow = (size_t)(kv0 + r) * 3072;
            gll16(Kbase + grow + cs, Ks   + ((rr<<8) + tid)*8);
            gll16(Vbase + grow + cs, Vlin + ((rr<<8) + tid)*8);
        }
    };

    auto pv = [&]() {
        wait_lgkm0();    // wave-private P writes complete
        bf16x8 pa[2][2];
        #pragma unroll
        for (int ks = 0; ks < 2; ++ks)
            #pragma unroll
            for (int qf = 0; qf < 2; ++qf) {
                int r = (qf << 4) + l15;
                int cc = ((ks << 5) + (lh << 3)) ^ ((r & 7) << 3);
                pa[ks][qf] = *(const bf16x8*)(Plw + r*64 + cc);
            }
        #pragma unroll
        for (int ks = 0; ks < 2; ++ks)
            #pragma unroll
            for (int df = 0; df < 4; ++df) {
                int r = (df << 4) + l15;
                int cc = ((ks << 5) + (lh << 3)) ^ ((r & 7) << 3);
                bf16x8 vb = *(const bf16x8*)(Vts + r*64 + cc);
                #pragma unroll
                for (int qf = 0; qf < 2; ++qf)
                    o[qf][df] = __builtin_amdgcn_mfma_f32_16x16x32_bf16(
                        pa[ks][qf], vb, o[qf][df], 0, 0, 0);
            }
    };

    auto compute = [&]() {
        // S = Q K^T  (per wave: 32 q x 64 kv)
        f32x4 p[2][4] = {};
        #pragma unroll
        for (int ks = 0; ks < 2; ++ks)
            #pragma unroll
            for (int nf = 0; nf < 4; ++nf) {
                int r = (nf << 4) + l15;
                int cc = ((ks << 5) + (lh << 3)) ^ ((r & 7) << 3);
                bf16x8 kf = *(const bf16x8*)(Ks + r*64 + cc);
                #pragma unroll
                for (int qf = 0; qf < 2; ++qf)
                    p[qf][nf] = __builtin_amdgcn_mfma_f32_16x16x32_bf16(
                        qfr[qf][ks], kf, p[qf][nf], 0, 0, 0);
            }
        // transpose V tile: Vlin[t][d] -> Vts[d][t]
        #pragma unroll
        for (int rr = 0; rr < 2; ++rr) {
            int t = l;
            int c = w + (rr << 2);
            bf16x8 vv = *(const bf16x8*)(Vlin + t*64 + ((c ^ (t & 7)) << 3));
            #pragma unroll
            for (int j = 0; j < 8; ++j)
                Vts[(c*8 + j)*64 + (t ^ (j << 3))] = vv[j];
        }
        // online softmax (exp2 domain, scale folded)
        #pragma unroll
        for (int qf = 0; qf < 2; ++qf)
            #pragma unroll
            for (int v = 0; v < 4; ++v) {
                float x0 = fmaxf(fmaxf(p[qf][0][v], p[qf][1][v]),
                                 fmaxf(p[qf][2][v], p[qf][3][v]));
                x0 = fmaxf(x0, __shfl_xor(x0, 1));
                x0 = fmaxf(x0, __shfl_xor(x0, 2));
                x0 = fmaxf(x0, __shfl_xor(x0, 4));
                x0 = fmaxf(x0, __shfl_xor(x0, 8));
                float mnew = fmaxf(mr[qf][v], x0 * SCALE);
                float alpha = exp2f(mr[qf][v] - mnew);
                mr[qf][v] = mnew;
                float ts = 0.f;
                #pragma unroll
                for (int nf = 0; nf < 4; ++nf) {
                    float e = exp2f(p[qf][nf][v] * SCALE - mnew);
                    p[qf][nf][v] = e;
                    ts += e;
                }
                ts += __shfl_xor(ts, 1);
                ts += __shfl_xor(ts, 2);
                ts += __shfl_xor(ts, 4);
                ts += __shfl_xor(ts, 8);
                sr[qf][v] = sr[qf][v] * alpha + ts;
                #pragma unroll
                for (int df = 0; df < 4; ++df)
                    o[qf][df][v] *= alpha;
            }
        // write P (bf16) to wave-private LDS
        #pragma unroll
        for (int qf = 0; qf < 2; ++qf)
            #pragma unroll
            for (int nf = 0; nf < 4; ++nf)
                #pragma unroll
                for (int v = 0; v < 4; ++v) {
                    int row = (qf << 4) + (lh << 2) + v;
                    int col = (nf << 4) + l15;
                    Plw[row*64 + (col ^ ((row & 7) << 3))] = f2bf(p[qf][nf][v]);
                }
    };

    stage(0);
    wait_vm0();
    __syncthreads();
    compute();
    __syncthreads();
    for (int it = 1; it < 32; ++it) {
        stage(it << 6);   // prefetch next K/Vlin (disjoint from Vts/P used by pv)
        pv();             // previous tile's PV overlaps the loads
        wait_vm0();
        __syncthreads();
        compute();
        __syncthreads();
    }
    pv();

    // epilogue: O = o / l, write [B,T,H*DH] bf16
    #pragma unroll
    for (int qf = 0; qf < 2; ++qf)
        #pragma unroll
        for (int v = 0; v < 4; ++v) {
            float inv = 1.0f / sr[qf][v];
            int t = qt0 + (w << 5) + (qf << 4) + (lh << 2) + v;
            size_t rowo = (size_t)((b << 11) + t) * 1024 + (h << 6);
            #pragma unroll
            for (int df = 0; df < 4; ++df)
                Ob[rowo + (df << 4) + l15] = f2bf(o[qf][df][v] * inv);
        }
}

extern "C" void kernel_launch(void* const* d_in, const int* in_sizes, int n_in,
                              void* d_out, int out_size, void* d_ws, size_t ws_size,
                              hipStream_t stream)
{
    const float* x     = (const float*)d_in[0];
    const float* w_qkv = (const float*)d_in[1];
    const float* b_qkv = (const float*)d_in[2];
    const float* w_out = (const float*)d_in[3];
    const float* b_out = (const float*)d_in[4];
    float* out = (float*)d_out;

    // workspace layout (bf16 shorts): qkv | wqb | wob | xb(=Ob)
    short* qkv = (short*)d_ws;                      // 8192*3072
    short* wqb = qkv + (size_t)8192*3072;           // 3072*1024
    short* wob = wqb + (size_t)3072*1024;           // 1024*1024
    short* xb  = wob + (size_t)1024*1024;           // 8192*1024 (reused as Ob)
    short* Ob  = xb;

    k_convert<<<2048, 256, 0, stream>>>(x, xb, w_qkv, wqb, w_out, wob);
    k_gemm<0><<<dim3(64, 24), 256, 0, stream>>>(xb, wqb, b_qkv, (void*)qkv, 3072, 1024);
    k_attn<<<dim3(16, 64), 256, 0, stream>>>(qkv, Ob);
    k_gemm<1><<<dim3(64, 8), 256, 0, stream>>>(Ob, wob, b_out, (void*)out, 1024, 1024);
}

// Round 3
// 559.787 us; speedup vs baseline: 1.0820x; 1.0820x over previous
//
#include <hip/hip_runtime.h>
#include <stdint.h>

typedef __attribute__((ext_vector_type(8))) short bf16x8;
typedef __attribute__((ext_vector_type(4))) short s16x4;
typedef __attribute__((ext_vector_type(4))) float f32x4;

#define DEV static __device__ __forceinline__

DEV short f2bf(float f) {
    union { float f; uint32_t u; } v; v.f = f;
    uint32_t r = (v.u + 0x7fffu + ((v.u >> 16) & 1u)) >> 16;
    return (short)r;
}

DEV void gll16(const void* g, void* l) {
    __builtin_amdgcn_global_load_lds(
        (const __attribute__((address_space(1))) uint32_t*)g,
        (__attribute__((address_space(3))) uint32_t*)l, 16, 0, 0);
}

DEV void wait_vm0()   { asm volatile("s_waitcnt vmcnt(0)" ::: "memory"); }
DEV void wait_vm4()   { asm volatile("s_waitcnt vmcnt(4)" ::: "memory"); }
DEV void wait_lgkm0() { asm volatile("s_waitcnt lgkmcnt(0)" ::: "memory"); }

// ---------------- fp32 -> bf16 convert ----------------
__global__ __launch_bounds__(256) void k_convert(
    const float* __restrict__ x,  short* __restrict__ xb,
    const float* __restrict__ wq, short* __restrict__ wqb,
    const float* __restrict__ wo, short* __restrict__ wob)
{
    const int NX = (8192*1024)/4, NW = (3072*1024)/4, NO = (1024*1024)/4;
    const int total = NX + NW + NO;
    for (int i = blockIdx.x*blockDim.x + threadIdx.x; i < total; i += gridDim.x*blockDim.x) {
        const float* s; short* d; int j;
        if (i < NX)           { s = x;  d = xb;  j = i; }
        else if (i < NX + NW) { s = wq; d = wqb; j = i - NX; }
        else                  { s = wo; d = wob; j = i - NX - NW; }
        f32x4 v = *(const f32x4*)(s + (size_t)j*4);
        s16x4 o;
        o[0] = f2bf(v[0]); o[1] = f2bf(v[1]); o[2] = f2bf(v[2]); o[3] = f2bf(v[3]);
        *(s16x4*)(d + (size_t)j*4) = o;
    }
}

// ---------------- NT GEMM: C[m][n] = sum_k A[m][k]*Bw[n][k] + bias[n] ----------------
// MODE 0 (QKV): n<2048 -> bf16 qk[8192][2048]; n>=2048 -> V transposed into
//               Vt[b*16+h][d][t] (bf16 [64][64][2048]).  MODE 1: fp32 direct.
template<int MODE>
__global__ __launch_bounds__(256) void k_gemm(
    const short* __restrict__ A,    // [Mtot][K] bf16
    const short* __restrict__ Bw,   // [Ntot][K] bf16
    const float* __restrict__ bias, // [Ntot] fp32
    void* __restrict__ Cout,        // MODE0: qk base; MODE1: fp32 out
    void* __restrict__ Cout2,       // MODE0: Vt base; MODE1: unused
    int Nld, int K)
{
    __shared__ short smem[17408];       // As[8192] | Bs[8192]; epilogue C[128][136]
    short* As = smem;
    short* Bs = smem + 8192;
    const int tid = threadIdx.x;
    const int l = tid & 63, w = tid >> 6;
    const int bm = blockIdx.x << 7, bn = blockIdx.y << 7;
    const int wm = (w >> 1) << 6, wn = (w & 1) << 6;
    const int l15 = l & 15, lh = l >> 4;
    const int rS = tid >> 3, cS = tid & 7;   // staging: row chunk within 32-row round

    f32x4 acc[4][4] = {};
    const int KT = K >> 6;

    for (int kt = 0; kt < KT; ++kt) {
        const int k0 = kt << 6;
        #pragma unroll
        for (int rr = 0; rr < 4; ++rr) {
            int r = (rr << 5) + rS;
            int cs = (cS ^ (r & 7)) << 3;            // pre-swizzled global source
            gll16(A  + (size_t)(bm + r)*K + k0 + cs, As + ((rr<<8) + tid)*8);
            gll16(Bw + (size_t)(bn + r)*K + k0 + cs, Bs + ((rr<<8) + tid)*8);
        }
        wait_vm0();
        __syncthreads();

        bf16x8 af[2][4], bfr[2][4];
        #pragma unroll
        for (int ks = 0; ks < 2; ++ks) {
            #pragma unroll
            for (int mf = 0; mf < 4; ++mf) {
                int r = wm + (mf << 4) + l15;
                int cc = ((ks << 5) + (lh << 3)) ^ ((r & 7) << 3);
                af[ks][mf] = *(const bf16x8*)(As + r*64 + cc);
            }
            #pragma unroll
            for (int nf = 0; nf < 4; ++nf) {
                int r = wn + (nf << 4) + l15;
                int cc = ((ks << 5) + (lh << 3)) ^ ((r & 7) << 3);
                bfr[ks][nf] = *(const bf16x8*)(Bs + r*64 + cc);
            }
        }
        #pragma unroll
        for (int ks = 0; ks < 2; ++ks)
            #pragma unroll
            for (int mf = 0; mf < 4; ++mf)
                #pragma unroll
                for (int nf = 0; nf < 4; ++nf)
                    acc[mf][nf] = __builtin_amdgcn_mfma_f32_16x16x32_bf16(
                        af[ks][mf], bfr[ks][nf], acc[mf][nf], 0, 0, 0);
        __syncthreads();
    }

    float bv[4];
    #pragma unroll
    for (int nf = 0; nf < 4; ++nf) bv[nf] = bias[bn + wn + (nf<<4) + l15];

    if (MODE == 0) {
        #pragma unroll
        for (int mf = 0; mf < 4; ++mf)
            #pragma unroll
            for (int nf = 0; nf < 4; ++nf)
                #pragma unroll
                for (int v = 0; v < 4; ++v) {
                    int r = wm + (mf<<4) + (lh<<2) + v;
                    int c = wn + (nf<<4) + l15;
                    smem[r*136 + c] = f2bf(acc[mf][nf][v] + bv[nf]);
                }
        __syncthreads();
        if (bn < 2048) {
            int r = tid >> 1, half = tid & 1;
            const short* src = smem + r*136 + (half << 6);
            short* dst = (short*)Cout + (size_t)(bm + r)*2048 + bn + (half << 6);
            #pragma unroll
            for (int c = 0; c < 8; ++c)
                *(bf16x8*)(dst + (c<<3)) = *(const bf16x8*)(src + (c<<3));
        } else {
            // transposed store of V columns: Vt[(b*16+h)][d][t]
            int nl = tid >> 1;                 // 0..127 (n within tile)
            int nloc = (bn - 2048) + nl;
            int hh = nloc >> 6, d = nloc & 63;
            int tl0 = (tid & 1) << 6;          // 0 or 64 (t within tile)
            int bb = bm >> 11;
            int tt0 = (bm & 2047) + tl0;
            short* dst = (short*)Cout2 + (((size_t)((bb << 4) + hh) << 6) + d) * 2048 + tt0;
            #pragma unroll
            for (int c = 0; c < 8; ++c) {
                bf16x8 pk;
                #pragma unroll
                for (int j = 0; j < 8; ++j)
                    pk[j] = smem[(tl0 + (c<<3) + j)*136 + nl];
                *(bf16x8*)(dst + (c<<3)) = pk;
            }
        }
    } else {
        float* C = (float*)Cout;
        #pragma unroll
        for (int mf = 0; mf < 4; ++mf)
            #pragma unroll
            for (int nf = 0; nf < 4; ++nf)
                #pragma unroll
                for (int v = 0; v < 4; ++v) {
                    int r = bm + wm + (mf<<4) + (lh<<2) + v;
                    int c = bn + wn + (nf<<4) + l15;
                    C[(size_t)r*Nld + c] = acc[mf][nf][v] + bv[nf];
                }
    }
}

// ---------------- flash attention (double-buffered, counted vmcnt) ----------------
// qk: [8192][2048] bf16 rows m=b*2048+t, cols: Q h*64+d | K 1024+h*64+d
// Vt: [64 bh][64 d][2048 t] bf16
// Ob: [8192][1024] bf16
__global__ __launch_bounds__(256) void k_attn(
    const short* __restrict__ qk, const short* __restrict__ Vt,
    short* __restrict__ Ob)
{
    __shared__ short Kd[2][4096];    // K tile  [64 kv][64 d]  (swizzled, dbuf)
    __shared__ short Vs[2][4096];    // V^T tile [64 d][64 kv] (swizzled, dbuf)
    __shared__ short Pl[4][2048];    // per-wave P [32 q][64 kv] (swizzled)

    const int tid = threadIdx.x;
    const int l = tid & 63, w = tid >> 6;
    const int l15 = l & 15, lh = l >> 4;
    const int qt0 = blockIdx.x << 7;
    const int bh = blockIdx.y;
    const int b = bh >> 4, h = bh & 15;
    const short* Qbase = qk + (size_t)(b << 11) * 2048 + (h << 6);
    const short* Kbase = Qbase + 1024;
    const short* Vtg = Vt + ((size_t)bh << 17);    // 64*2048 per (b,h)
    short* Plw = &Pl[w][0];
    const int rS = tid >> 3, cS = tid & 7;

    // Q fragments in registers for the whole block lifetime
    bf16x8 qfr[2][2];
    #pragma unroll
    for (int qf = 0; qf < 2; ++qf)
        #pragma unroll
        for (int ks = 0; ks < 2; ++ks) {
            int t = qt0 + (w << 5) + (qf << 4) + l15;
            qfr[qf][ks] = *(const bf16x8*)(Qbase + (size_t)t*2048 + (ks << 5) + (lh << 3));
        }

    f32x4 o[2][4] = {};
    float mr[2][4], sr[2][4];
    #pragma unroll
    for (int qf = 0; qf < 2; ++qf)
        #pragma unroll
        for (int v = 0; v < 4; ++v) { mr[qf][v] = -__builtin_inff(); sr[qf][v] = 0.f; }
    const float SCALE = 0.125f * 1.44269504088896341f;   // (1/sqrt(64)) * log2(e)

    auto stage = [&](int kv0, int buf) {
        #pragma unroll
        for (int rr = 0; rr < 2; ++rr) {
            int r = (rr << 5) + rS;
            int cs = (cS ^ (r & 7)) << 3;
            gll16(Kbase + (size_t)(kv0 + r)*2048 + cs, &Kd[buf][((rr<<8) + tid)*8]);
            gll16(Vtg + ((size_t)r << 11) + kv0 + cs,  &Vs[buf][((rr<<8) + tid)*8]);
        }
    };

    auto tile_compute = [&](int cur) {
        // S = Q K^T  (per wave: 32 q x 64 kv)
        f32x4 p[2][4] = {};
        #pragma unroll
        for (int ks = 0; ks < 2; ++ks)
            #pragma unroll
            for (int nf = 0; nf < 4; ++nf) {
                int r = (nf << 4) + l15;
                int cc = ((ks << 5) + (lh << 3)) ^ ((r & 7) << 3);
                bf16x8 kf = *(const bf16x8*)(&Kd[cur][r*64 + cc]);
                #pragma unroll
                for (int qf = 0; qf < 2; ++qf)
                    p[qf][nf] = __builtin_amdgcn_mfma_f32_16x16x32_bf16(
                        qfr[qf][ks], kf, p[qf][nf], 0, 0, 0);
            }
        // online softmax (exp2 domain, scale folded)
        #pragma unroll
        for (int qf = 0; qf < 2; ++qf)
            #pragma unroll
            for (int v = 0; v < 4; ++v) {
                float x0 = fmaxf(fmaxf(p[qf][0][v], p[qf][1][v]),
                                 fmaxf(p[qf][2][v], p[qf][3][v]));
                x0 = fmaxf(x0, __shfl_xor(x0, 1));
                x0 = fmaxf(x0, __shfl_xor(x0, 2));
                x0 = fmaxf(x0, __shfl_xor(x0, 4));
                x0 = fmaxf(x0, __shfl_xor(x0, 8));
                float mnew = fmaxf(mr[qf][v], x0 * SCALE);
                float alpha = exp2f(mr[qf][v] - mnew);
                mr[qf][v] = mnew;
                float ts = 0.f;
                #pragma unroll
                for (int nf = 0; nf < 4; ++nf) {
                    float e = exp2f(p[qf][nf][v] * SCALE - mnew);
                    p[qf][nf][v] = e;
                    ts += e;
                }
                ts += __shfl_xor(ts, 1);
                ts += __shfl_xor(ts, 2);
                ts += __shfl_xor(ts, 4);
                ts += __shfl_xor(ts, 8);
                sr[qf][v] = sr[qf][v] * alpha + ts;
                #pragma unroll
                for (int df = 0; df < 4; ++df)
                    o[qf][df][v] *= alpha;
            }
        // write P (bf16) to wave-private LDS
        #pragma unroll
        for (int qf = 0; qf < 2; ++qf)
            #pragma unroll
            for (int nf = 0; nf < 4; ++nf)
                #pragma unroll
                for (int v = 0; v < 4; ++v) {
                    int row = (qf << 4) + (lh << 2) + v;
                    int col = (nf << 4) + l15;
                    Plw[row*64 + (col ^ ((row & 7) << 3))] = f2bf(p[qf][nf][v]);
                }
        // PV
        wait_lgkm0();
        bf16x8 pa[2][2];
        #pragma unroll
        for (int ks = 0; ks < 2; ++ks)
            #pragma unroll
            for (int qf = 0; qf < 2; ++qf) {
                int r = (qf << 4) + l15;
                int cc = ((ks << 5) + (lh << 3)) ^ ((r & 7) << 3);
                pa[ks][qf] = *(const bf16x8*)(Plw + r*64 + cc);
            }
        #pragma unroll
        for (int ks = 0; ks < 2; ++ks)
            #pragma unroll
            for (int df = 0; df < 4; ++df) {
                int r = (df << 4) + l15;
                int cc = ((ks << 5) + (lh << 3)) ^ ((r & 7) << 3);
                bf16x8 vb = *(const bf16x8*)(&Vs[cur][r*64 + cc]);
                #pragma unroll
                for (int qf = 0; qf < 2; ++qf)
                    o[qf][df] = __builtin_amdgcn_mfma_f32_16x16x32_bf16(
                        pa[ks][qf], vb, o[qf][df], 0, 0, 0);
            }
    };

    stage(0, 0);
    for (int it = 0; it < 31; ++it) {
        int cur = it & 1;
        stage((it + 1) << 6, cur ^ 1);   // issue next tile BEFORE computing current
        wait_vm4();                      // current tile's 4 loads (older) complete
        __syncthreads();                 // publish tile
        tile_compute(cur);
        __syncthreads();                 // protect buf before next-iter overwrite
    }
    wait_vm0();
    __syncthreads();
    tile_compute(1);                     // it=31

    // epilogue: O = o / l, write [B,T,H*DH] bf16
    #pragma unroll
    for (int qf = 0; qf < 2; ++qf)
        #pragma unroll
        for (int v = 0; v < 4; ++v) {
            float inv = 1.0f / sr[qf][v];
            int t = qt0 + (w << 5) + (qf << 4) + (lh << 2) + v;
            size_t rowo = (size_t)((b << 11) + t) * 1024 + (h << 6);
            #pragma unroll
            for (int df = 0; df < 4; ++df)
                Ob[rowo + (df << 4) + l15] = f2bf(o[qf][df][v] * inv);
        }
}

extern "C" void kernel_launch(void* const* d_in, const int* in_sizes, int n_in,
                              void* d_out, int out_size, void* d_ws, size_t ws_size,
                              hipStream_t stream)
{
    const float* x     = (const float*)d_in[0];
    const float* w_qkv = (const float*)d_in[1];
    const float* b_qkv = (const float*)d_in[2];
    const float* w_out = (const float*)d_in[3];
    const float* b_out = (const float*)d_in[4];
    float* out = (float*)d_out;

    // workspace layout (bf16 shorts): qk | Vt | wqb | wob | xb(=Ob)
    short* qk  = (short*)d_ws;                       // 8192*2048
    short* Vt  = qk  + (size_t)8192*2048;            // 64*64*2048
    short* wqb = Vt  + (size_t)64*64*2048;           // 3072*1024
    short* wob = wqb + (size_t)3072*1024;            // 1024*1024
    short* xb  = wob + (size_t)1024*1024;            // 8192*1024 (reused as Ob)
    short* Ob  = xb;

    k_convert<<<2048, 256, 0, stream>>>(x, xb, w_qkv, wqb, w_out, wob);
    k_gemm<0><<<dim3(64, 24), 256, 0, stream>>>(xb, wqb, b_qkv, (void*)qk, (void*)Vt, 2048, 1024);
    k_attn<<<dim3(16, 64), 256, 0, stream>>>(qk, Vt, Ob);
    k_gemm<1><<<dim3(64, 8), 256, 0, stream>>>(Ob, wob, b_out, (void*)out, (void*)nullptr, 1024, 1024);
}

// Round 6
// 363.962 us; speedup vs baseline: 1.6641x; 1.5380x over previous
//
#include <hip/hip_runtime.h>
#include <stdint.h>

typedef __attribute__((ext_vector_type(8))) short bf16x8;
typedef __attribute__((ext_vector_type(4))) short s16x4;
typedef __attribute__((ext_vector_type(4))) float f32x4;

#define DEV static __device__ __forceinline__

DEV short f2bf(float f) {
    union { float f; uint32_t u; } v; v.f = f;
    uint32_t r = (v.u + 0x7fffu + ((v.u >> 16) & 1u)) >> 16;
    return (short)r;
}

DEV void gll16(const void* g, void* l) {
    __builtin_amdgcn_global_load_lds(
        (const __attribute__((address_space(1))) uint32_t*)g,
        (__attribute__((address_space(3))) uint32_t*)l, 16, 0, 0);
}

DEV void wait_vm0()   { asm volatile("s_waitcnt vmcnt(0)" ::: "memory"); }
DEV void wait_vm4()   { asm volatile("s_waitcnt vmcnt(4)" ::: "memory"); }
DEV void wait_lgkm0() { asm volatile("s_waitcnt lgkmcnt(0)" ::: "memory"); }

// ---------------- fp32 -> bf16 convert ----------------
__global__ __launch_bounds__(256) void k_convert(
    const float* __restrict__ x,  short* __restrict__ xb,
    const float* __restrict__ wq, short* __restrict__ wqb,
    const float* __restrict__ wo, short* __restrict__ wob)
{
    const int NX = (8192*1024)/4, NW = (3072*1024)/4, NO = (1024*1024)/4;
    const int total = NX + NW + NO;
    for (int i = blockIdx.x*blockDim.x + threadIdx.x; i < total; i += gridDim.x*blockDim.x) {
        const float* s; short* d; int j;
        if (i < NX)           { s = x;  d = xb;  j = i; }
        else if (i < NX + NW) { s = wq; d = wqb; j = i - NX; }
        else                  { s = wo; d = wob; j = i - NX - NW; }
        f32x4 v = *(const f32x4*)(s + (size_t)j*4);
        s16x4 o;
        o[0] = f2bf(v[0]); o[1] = f2bf(v[1]); o[2] = f2bf(v[2]); o[3] = f2bf(v[3]);
        *(s16x4*)(d + (size_t)j*4) = o;
    }
}

// ---------------- NT GEMM: C[m][n] = sum_k A[m][k]*Bw[n][k] + bias[n] ----------------
// MODE 0 (QKV): n<2048 -> bf16 qk[8192][2048]; n>=2048 -> V transposed into
//               Vt[b*16+h][d][t] (bf16 [64][64][2048]).  MODE 1: fp32 direct.
template<int MODE>
__global__ __launch_bounds__(256) void k_gemm(
    const short* __restrict__ A,    // [Mtot][K] bf16
    const short* __restrict__ Bw,   // [Ntot][K] bf16
    const float* __restrict__ bias, // [Ntot] fp32
    void* __restrict__ Cout,        // MODE0: qk base; MODE1: fp32 out
    void* __restrict__ Cout2,       // MODE0: Vt base; MODE1: unused
    int Nld, int K)
{
    __shared__ short smem[17408];       // As[8192] | Bs[8192]; epilogue C[128][136]
    short* As = smem;
    short* Bs = smem + 8192;
    const int tid = threadIdx.x;
    const int l = tid & 63, w = tid >> 6;
    const int bm = blockIdx.x << 7, bn = blockIdx.y << 7;
    const int wm = (w >> 1) << 6, wn = (w & 1) << 6;
    const int l15 = l & 15, lh = l >> 4;
    const int rS = tid >> 3, cS = tid & 7;   // staging: row chunk within 32-row round

    f32x4 acc[4][4] = {};
    const int KT = K >> 6;

    for (int kt = 0; kt < KT; ++kt) {
        const int k0 = kt << 6;
        #pragma unroll
        for (int rr = 0; rr < 4; ++rr) {
            int r = (rr << 5) + rS;
            int cs = (cS ^ (r & 7)) << 3;            // pre-swizzled global source
            gll16(A  + (size_t)(bm + r)*K + k0 + cs, As + ((rr<<8) + tid)*8);
            gll16(Bw + (size_t)(bn + r)*K + k0 + cs, Bs + ((rr<<8) + tid)*8);
        }
        wait_vm0();
        __syncthreads();

        bf16x8 af[2][4], bfr[2][4];
        #pragma unroll
        for (int ks = 0; ks < 2; ++ks) {
            #pragma unroll
            for (int mf = 0; mf < 4; ++mf) {
                int r = wm + (mf << 4) + l15;
                int cc = ((ks << 5) + (lh << 3)) ^ ((r & 7) << 3);
                af[ks][mf] = *(const bf16x8*)(As + r*64 + cc);
            }
            #pragma unroll
            for (int nf = 0; nf < 4; ++nf) {
                int r = wn + (nf << 4) + l15;
                int cc = ((ks << 5) + (lh << 3)) ^ ((r & 7) << 3);
                bfr[ks][nf] = *(const bf16x8*)(Bs + r*64 + cc);
            }
        }
        #pragma unroll
        for (int ks = 0; ks < 2; ++ks)
            #pragma unroll
            for (int mf = 0; mf < 4; ++mf)
                #pragma unroll
                for (int nf = 0; nf < 4; ++nf)
                    acc[mf][nf] = __builtin_amdgcn_mfma_f32_16x16x32_bf16(
                        af[ks][mf], bfr[ks][nf], acc[mf][nf], 0, 0, 0);
        __syncthreads();
    }

    float bv[4];
    #pragma unroll
    for (int nf = 0; nf < 4; ++nf) bv[nf] = bias[bn + wn + (nf<<4) + l15];

    if (MODE == 0) {
        #pragma unroll
        for (int mf = 0; mf < 4; ++mf)
            #pragma unroll
            for (int nf = 0; nf < 4; ++nf)
                #pragma unroll
                for (int v = 0; v < 4; ++v) {
                    int r = wm + (mf<<4) + (lh<<2) + v;
                    int c = wn + (nf<<4) + l15;
                    smem[r*136 + c] = f2bf(acc[mf][nf][v] + bv[nf]);
                }
        __syncthreads();
        if (bn < 2048) {
            int r = tid >> 1, half = tid & 1;
            const short* src = smem + r*136 + (half << 6);
            short* dst = (short*)Cout + (size_t)(bm + r)*2048 + bn + (half << 6);
            #pragma unroll
            for (int c = 0; c < 8; ++c)
                *(bf16x8*)(dst + (c<<3)) = *(const bf16x8*)(src + (c<<3));
        } else {
            // transposed store of V columns: Vt[(b*16+h)][d][t]
            int nl = tid >> 1;                 // 0..127 (n within tile)
            int nloc = (bn - 2048) + nl;
            int hh = nloc >> 6, d = nloc & 63;
            int tl0 = (tid & 1) << 6;          // 0 or 64 (t within tile)
            int bb = bm >> 11;
            int tt0 = (bm & 2047) + tl0;
            short* dst = (short*)Cout2 + (((size_t)((bb << 4) + hh) << 6) + d) * 2048 + tt0;
            #pragma unroll
            for (int c = 0; c < 8; ++c) {
                bf16x8 pk;
                #pragma unroll
                for (int j = 0; j < 8; ++j)
                    pk[j] = smem[(tl0 + (c<<3) + j)*136 + nl];
                *(bf16x8*)(dst + (c<<3)) = pk;
            }
        }
    } else {
        float* C = (float*)Cout;
        #pragma unroll
        for (int mf = 0; mf < 4; ++mf)
            #pragma unroll
            for (int nf = 0; nf < 4; ++nf)
                #pragma unroll
                for (int v = 0; v < 4; ++v) {
                    int r = bm + wm + (mf<<4) + (lh<<2) + v;
                    int c = bn + wn + (nf<<4) + l15;
                    C[(size_t)r*Nld + c] = acc[mf][nf][v] + bv[nf];
                }
    }
}

// ---------------- flash attention (swapped QK^T, in-reg softmax, LDS P handoff) ----
// qk: [8192][2048] bf16 rows m=b*2048+t, cols: Q h*64+d | K 1024+h*64+d
// Vt: [64 bh][64 d][2048 t] bf16
// Ob: [8192][1024] bf16
__global__ __launch_bounds__(256) void k_attn(
    const short* __restrict__ qk, const short* __restrict__ Vt,
    short* __restrict__ Ob)
{
    __shared__ short Kd[2][4096];    // K tile  [64 kv][64 d]   (swizzled, dbuf)
    __shared__ short Vs[2][4096];    // V^T tile [64 d][64 kv]  (swizzled, dbuf)
    __shared__ short Pl[4][2048];    // per-wave P [32 q][64 kv] (swizzled)

    const int tid = threadIdx.x;
    const int l = tid & 63, w = tid >> 6;
    const int l15 = l & 15, lh = l >> 4;
    const int qt0 = blockIdx.x << 7;
    const int bh = blockIdx.y;
    const int b = bh >> 4, h = bh & 15;
    const short* Qbase = qk + (size_t)(b << 11) * 2048 + (h << 6);
    const short* Kbase = Qbase + 1024;
    const short* Vtg = Vt + ((size_t)bh << 17);    // 64*2048 per (b,h)
    short* Plw = &Pl[w][0];
    const int rS = tid >> 3, cS = tid & 7;

    // Q fragments in registers for the whole block lifetime
    bf16x8 qfr[2][2];
    #pragma unroll
    for (int qf = 0; qf < 2; ++qf)
        #pragma unroll
        for (int ks = 0; ks < 2; ++ks) {
            int t = qt0 + (w << 5) + (qf << 4) + l15;
            qfr[qf][ks] = *(const bf16x8*)(Qbase + (size_t)t*2048 + (ks << 5) + (lh << 3));
        }

    f32x4 o[2][4] = {};
    float mr[2], sr[2];
    mr[0] = mr[1] = -__builtin_inff();
    sr[0] = sr[1] = 0.f;
    const float SCALE = 0.125f * 1.44269504088896341f;   // (1/sqrt(64)) * log2(e)

    auto stage = [&](int kv0, int buf) {
        #pragma unroll
        for (int rr = 0; rr < 2; ++rr) {
            int r = (rr << 5) + rS;
            int cs = (cS ^ (r & 7)) << 3;
            gll16(Kbase + (size_t)(kv0 + r)*2048 + cs, &Kd[buf][((rr<<8) + tid)*8]);
            gll16(Vtg + ((size_t)r << 11) + kv0 + cs,  &Vs[buf][((rr<<8) + tid)*8]);
        }
    };

    auto tile_compute = [&](int cur) {
        // P^T = K Q^T  (per wave: 64 kv x 32 q); lane holds P[kv=16mf+4lh+v][q=16qf+l15]
        f32x4 p2[4][2] = {};
        #pragma unroll
        for (int ks = 0; ks < 2; ++ks)
            #pragma unroll
            for (int mf = 0; mf < 4; ++mf) {
                int r = (mf << 4) + l15;
                int cc = ((ks << 5) + (lh << 3)) ^ ((r & 7) << 3);
                bf16x8 kf = *(const bf16x8*)(&Kd[cur][r*64 + cc]);
                #pragma unroll
                for (int qf = 0; qf < 2; ++qf)
                    p2[mf][qf] = __builtin_amdgcn_mfma_f32_16x16x32_bf16(
                        kf, qfr[qf][ks], p2[mf][qf], 0, 0, 0);
            }

        // in-register online softmax (q = l15 lane-local; 2 shuffles per reduce)
        #pragma unroll
        for (int qf = 0; qf < 2; ++qf) {
            float mt = p2[0][qf][0];
            #pragma unroll
            for (int mf = 0; mf < 4; ++mf)
                #pragma unroll
                for (int v = 0; v < 4; ++v)
                    if (mf | v) mt = fmaxf(mt, p2[mf][qf][v]);
            mt = fmaxf(mt, __shfl_xor(mt, 16));
            mt = fmaxf(mt, __shfl_xor(mt, 32));
            float mnew = fmaxf(mr[qf], mt * SCALE);
            float alpha = exp2f(mr[qf] - mnew);
            mr[qf] = mnew;
            float ts = 0.f;
            #pragma unroll
            for (int mf = 0; mf < 4; ++mf)
                #pragma unroll
                for (int v = 0; v < 4; ++v) {
                    float e = exp2f(p2[mf][qf][v] * SCALE - mnew);
                    p2[mf][qf][v] = e;
                    ts += e;
                }
            ts += __shfl_xor(ts, 16);
            ts += __shfl_xor(ts, 32);
            sr[qf] = sr[qf] * alpha + ts;
            #pragma unroll
            for (int df = 0; df < 4; ++df)
                #pragma unroll
                for (int v = 0; v < 4; ++v)
                    o[qf][df][v] *= alpha;
            // write P[q][kv] to wave-private LDS: row q = qf*16+l15, cols mf*16+lh*4+v
            int row = (qf << 4) + l15;
            int rs = (row & 7) << 3;
            #pragma unroll
            for (int mf = 0; mf < 4; ++mf) {
                s16x4 st;
                #pragma unroll
                for (int v = 0; v < 4; ++v)
                    st[v] = f2bf(p2[mf][qf][v]);
                *(s16x4*)(Plw + row*64 + (((mf << 4) + (lh << 2)) ^ rs)) = st;
            }
        }

        // PV: O^T += V^T · P  (A = V^T rows d, B = P rows q; D[d][q])
        wait_lgkm0();
        bf16x8 pa[2][2];
        #pragma unroll
        for (int ks = 0; ks < 2; ++ks)
            #pragma unroll
            for (int qf = 0; qf < 2; ++qf) {
                int r = (qf << 4) + l15;
                int cc = ((ks << 5) + (lh << 3)) ^ ((r & 7) << 3);
                pa[ks][qf] = *(const bf16x8*)(Plw + r*64 + cc);
            }
        #pragma unroll
        for (int ks = 0; ks < 2; ++ks)
            #pragma unroll
            for (int df = 0; df < 4; ++df) {
                int r = (df << 4) + l15;
                int cc = ((ks << 5) + (lh << 3)) ^ ((r & 7) << 3);
                bf16x8 vb = *(const bf16x8*)(&Vs[cur][r*64 + cc]);
                #pragma unroll
                for (int qf = 0; qf < 2; ++qf)
                    o[qf][df] = __builtin_amdgcn_mfma_f32_16x16x32_bf16(
                        vb, pa[ks][qf], o[qf][df], 0, 0, 0);
            }
    };

    stage(0, 0);
    for (int it = 0; it < 31; ++it) {
        int cur = it & 1;
        stage((it + 1) << 6, cur ^ 1);   // issue next tile BEFORE computing current
        wait_vm4();                      // current tile's 4 loads (older) complete
        __syncthreads();                 // publish tile
        tile_compute(cur);
        __syncthreads();                 // protect buf before next-iter overwrite
    }
    wait_vm0();
    __syncthreads();
    tile_compute(1);                     // it=31

    // epilogue: O[q][d] = o^T / sr; q = l15, d = df*16 + lh*4 + v
    #pragma unroll
    for (int qf = 0; qf < 2; ++qf) {
        float inv = 1.0f / sr[qf];
        int t = qt0 + (w << 5) + (qf << 4) + l15;
        short* rowp = Ob + (size_t)((b << 11) + t) * 1024 + (h << 6);
        #pragma unroll
        for (int df = 0; df < 4; ++df) {
            s16x4 st;
            #pragma unroll
            for (int v = 0; v < 4; ++v)
                st[v] = f2bf(o[qf][df][v] * inv);
            *(s16x4*)(rowp + (df << 4) + (lh << 2)) = st;
        }
    }
}

extern "C" void kernel_launch(void* const* d_in, const int* in_sizes, int n_in,
                              void* d_out, int out_size, void* d_ws, size_t ws_size,
                              hipStream_t stream)
{
    const float* x     = (const float*)d_in[0];
    const float* w_qkv = (const float*)d_in[1];
    const float* b_qkv = (const float*)d_in[2];
    const float* w_out = (const float*)d_in[3];
    const float* b_out = (const float*)d_in[4];
    float* out = (float*)d_out;

    // workspace layout (bf16 shorts): qk | Vt | wqb | wob | xb(=Ob)
    short* qk  = (short*)d_ws;                       // 8192*2048
    short* Vt  = qk  + (size_t)8192*2048;            // 64*64*2048
    short* wqb = Vt  + (size_t)64*64*2048;           // 3072*1024
    short* wob = wqb + (size_t)3072*1024;            // 1024*1024
    short* xb  = wob + (size_t)1024*1024;            // 8192*1024 (reused as Ob)
    short* Ob  = xb;

    k_convert<<<2048, 256, 0, stream>>>(x, xb, w_qkv, wqb, w_out, wob);
    k_gemm<0><<<dim3(64, 24), 256, 0, stream>>>(xb, wqb, b_qkv, (void*)qk, (void*)Vt, 2048, 1024);
    k_attn<<<dim3(16, 64), 256, 0, stream>>>(qk, Vt, Ob);
    k_gemm<1><<<dim3(64, 8), 256, 0, stream>>>(Ob, wob, b_out, (void*)out, (void*)nullptr, 1024, 1024);
}

// Round 7
// 331.655 us; speedup vs baseline: 1.8263x; 1.0974x over previous
//
#include <hip/hip_runtime.h>
#include <stdint.h>

typedef __attribute__((ext_vector_type(8))) short bf16x8;
typedef __attribute__((ext_vector_type(4))) short s16x4;
typedef __attribute__((ext_vector_type(4))) float f32x4;
typedef __attribute__((ext_vector_type(2))) int i32x2;

#define DEV static __device__ __forceinline__

DEV short f2bf(float f) {
    union { float f; uint32_t u; } v; v.f = f;
    uint32_t r = (v.u + 0x7fffu + ((v.u >> 16) & 1u)) >> 16;
    return (short)r;
}

DEV int cvtpk(float lo, float hi) {   // [15:0]=bf16(lo), [31:16]=bf16(hi), RNE
    int r;
    asm("v_cvt_pk_bf16_f32 %0, %1, %2" : "=v"(r) : "v"(lo), "v"(hi));
    return r;
}

DEV float exp2n(float x) { return __builtin_amdgcn_exp2f(x); }

DEV void gll16(const void* g, void* l) {
    __builtin_amdgcn_global_load_lds(
        (const __attribute__((address_space(1))) uint32_t*)g,
        (__attribute__((address_space(3))) uint32_t*)l, 16, 0, 0);
}

DEV void wait_vm0()   { asm volatile("s_waitcnt vmcnt(0)" ::: "memory"); }
DEV void wait_vm4()   { asm volatile("s_waitcnt vmcnt(4)" ::: "memory"); }
DEV void wait_lgkm0() { asm volatile("s_waitcnt lgkmcnt(0)" ::: "memory"); }

// ---------------- fp32 -> bf16 convert ----------------
__global__ __launch_bounds__(256) void k_convert(
    const float* __restrict__ x,  short* __restrict__ xb,
    const float* __restrict__ wq, short* __restrict__ wqb,
    const float* __restrict__ wo, short* __restrict__ wob)
{
    const int NX = (8192*1024)/4, NW = (3072*1024)/4, NO = (1024*1024)/4;
    const int total = NX + NW + NO;
    for (int i = blockIdx.x*blockDim.x + threadIdx.x; i < total; i += gridDim.x*blockDim.x) {
        const float* s; short* d; int j;
        if (i < NX)           { s = x;  d = xb;  j = i; }
        else if (i < NX + NW) { s = wq; d = wqb; j = i - NX; }
        else                  { s = wo; d = wob; j = i - NX - NW; }
        f32x4 v = *(const f32x4*)(s + (size_t)j*4);
        s16x4 o;
        o[0] = f2bf(v[0]); o[1] = f2bf(v[1]); o[2] = f2bf(v[2]); o[3] = f2bf(v[3]);
        *(s16x4*)(d + (size_t)j*4) = o;
    }
}

// ---------------- NT GEMM: C[m][n] = sum_k A[m][k]*Bw[n][k] + bias[n] ----------------
// MODE 0 (QKV): n<2048 -> bf16 qk[8192][2048]; n>=2048 -> V transposed into
//               Vt[b*16+h][d][t] (bf16 [64][64][2048]).  MODE 1: fp32 direct.
// Block->tile map is XCD-swizzled (bijective: nwg % 8 == 0 for both launches).
template<int MODE>
__global__ __launch_bounds__(256) void k_gemm(
    const short* __restrict__ A,    // [Mtot][K] bf16
    const short* __restrict__ Bw,   // [Ntot][K] bf16
    const float* __restrict__ bias, // [Ntot] fp32
    void* __restrict__ Cout,        // MODE0: qk base; MODE1: fp32 out
    void* __restrict__ Cout2,       // MODE0: Vt base; MODE1: unused
    int Nld, int K)
{
    __shared__ short smem[17408];       // As[8192] | Bs[8192]; epilogue C[128][136]
    short* As = smem;
    short* Bs = smem + 8192;
    const int tid = threadIdx.x;
    const int l = tid & 63, w = tid >> 6;
    // XCD-aware bijective swizzle: consecutive idx within an XCD walk m-tiles
    const int lin = blockIdx.y * 64 + blockIdx.x;
    const int per = (gridDim.y << 6) >> 3;
    const int idx = (lin & 7) * per + (lin >> 3);
    const int bm = (idx & 63) << 7, bn = (idx >> 6) << 7;
    const int wm = (w >> 1) << 6, wn = (w & 1) << 6;
    const int l15 = l & 15, lh = l >> 4;
    const int rS = tid >> 3, cS = tid & 7;   // staging: row chunk within 32-row round

    f32x4 acc[4][4] = {};
    const int KT = K >> 6;

    for (int kt = 0; kt < KT; ++kt) {
        const int k0 = kt << 6;
        #pragma unroll
        for (int rr = 0; rr < 4; ++rr) {
            int r = (rr << 5) + rS;
            int cs = (cS ^ (r & 7)) << 3;            // pre-swizzled global source
            gll16(A  + (size_t)(bm + r)*K + k0 + cs, As + ((rr<<8) + tid)*8);
            gll16(Bw + (size_t)(bn + r)*K + k0 + cs, Bs + ((rr<<8) + tid)*8);
        }
        wait_vm0();
        __syncthreads();

        bf16x8 af[2][4], bfr[2][4];
        #pragma unroll
        for (int ks = 0; ks < 2; ++ks) {
            #pragma unroll
            for (int mf = 0; mf < 4; ++mf) {
                int r = wm + (mf << 4) + l15;
                int cc = ((ks << 5) + (lh << 3)) ^ ((r & 7) << 3);
                af[ks][mf] = *(const bf16x8*)(As + r*64 + cc);
            }
            #pragma unroll
            for (int nf = 0; nf < 4; ++nf) {
                int r = wn + (nf << 4) + l15;
                int cc = ((ks << 5) + (lh << 3)) ^ ((r & 7) << 3);
                bfr[ks][nf] = *(const bf16x8*)(Bs + r*64 + cc);
            }
        }
        #pragma unroll
        for (int ks = 0; ks < 2; ++ks)
            #pragma unroll
            for (int mf = 0; mf < 4; ++mf)
                #pragma unroll
                for (int nf = 0; nf < 4; ++nf)
                    acc[mf][nf] = __builtin_amdgcn_mfma_f32_16x16x32_bf16(
                        af[ks][mf], bfr[ks][nf], acc[mf][nf], 0, 0, 0);
        __syncthreads();
    }

    float bv[4];
    #pragma unroll
    for (int nf = 0; nf < 4; ++nf) bv[nf] = bias[bn + wn + (nf<<4) + l15];

    if (MODE == 0) {
        #pragma unroll
        for (int mf = 0; mf < 4; ++mf)
            #pragma unroll
            for (int nf = 0; nf < 4; ++nf)
                #pragma unroll
                for (int v = 0; v < 4; ++v) {
                    int r = wm + (mf<<4) + (lh<<2) + v;
                    int c = wn + (nf<<4) + l15;
                    smem[r*136 + c] = f2bf(acc[mf][nf][v] + bv[nf]);
                }
        __syncthreads();
        if (bn < 2048) {
            int r = tid >> 1, half = tid & 1;
            const short* src = smem + r*136 + (half << 6);
            short* dst = (short*)Cout + (size_t)(bm + r)*2048 + bn + (half << 6);
            #pragma unroll
            for (int c = 0; c < 8; ++c)
                *(bf16x8*)(dst + (c<<3)) = *(const bf16x8*)(src + (c<<3));
        } else {
            // transposed store of V columns: Vt[(b*16+h)][d][t]
            int nl = tid >> 1;                 // 0..127 (n within tile)
            int nloc = (bn - 2048) + nl;
            int hh = nloc >> 6, d = nloc & 63;
            int tl0 = (tid & 1) << 6;          // 0 or 64 (t within tile)
            int bb = bm >> 11;
            int tt0 = (bm & 2047) + tl0;
            short* dst = (short*)Cout2 + (((size_t)((bb << 4) + hh) << 6) + d) * 2048 + tt0;
            #pragma unroll
            for (int c = 0; c < 8; ++c) {
                bf16x8 pk;
                #pragma unroll
                for (int j = 0; j < 8; ++j)
                    pk[j] = smem[(tl0 + (c<<3) + j)*136 + nl];
                *(bf16x8*)(dst + (c<<3)) = pk;
            }
        }
    } else {
        float* C = (float*)Cout;
        #pragma unroll
        for (int mf = 0; mf < 4; ++mf)
            #pragma unroll
            for (int nf = 0; nf < 4; ++nf)
                #pragma unroll
                for (int v = 0; v < 4; ++v) {
                    int r = bm + wm + (mf<<4) + (lh<<2) + v;
                    int c = bn + wn + (nf<<4) + l15;
                    C[(size_t)r*Nld + c] = acc[mf][nf][v] + bv[nf];
                }
    }
}

// ---------------- flash attention (swapped QK^T, in-reg softmax, LDS P handoff) ----
// qk: [8192][2048] bf16 rows m=b*2048+t, cols: Q h*64+d | K 1024+h*64+d
// Vt: [64 bh][64 d][2048 t] bf16
// Ob: [8192][1024] bf16
__global__ __launch_bounds__(256) void k_attn(
    const short* __restrict__ qk, const short* __restrict__ Vt,
    short* __restrict__ Ob)
{
    __shared__ short Kd[2][4096];    // K tile  [64 kv][64 d]   (swizzled, dbuf)
    __shared__ short Vs[2][4096];    // V^T tile [64 d][64 kv]  (swizzled, dbuf)
    __shared__ short Pl[4][2048];    // per-wave P [32 q][64 kv] (swizzled)

    const int tid = threadIdx.x;
    const int l = tid & 63, w = tid >> 6;
    const int l15 = l & 15, lh = l >> 4;
    const int qt0 = blockIdx.x << 7;
    const int bh = blockIdx.y;
    const int b = bh >> 4, h = bh & 15;
    const short* Qbase = qk + (size_t)(b << 11) * 2048 + (h << 6);
    const short* Kbase = Qbase + 1024;
    const short* Vtg = Vt + ((size_t)bh << 17);    // 64*2048 per (b,h)
    short* Plw = &Pl[w][0];
    const int rS = tid >> 3, cS = tid & 7;

    // Q fragments in registers for the whole block lifetime
    bf16x8 qfr[2][2];
    #pragma unroll
    for (int qf = 0; qf < 2; ++qf)
        #pragma unroll
        for (int ks = 0; ks < 2; ++ks) {
            int t = qt0 + (w << 5) + (qf << 4) + l15;
            qfr[qf][ks] = *(const bf16x8*)(Qbase + (size_t)t*2048 + (ks << 5) + (lh << 3));
        }

    f32x4 o[2][4] = {};
    float mr[2], sr[2];
    mr[0] = mr[1] = -__builtin_inff();
    sr[0] = sr[1] = 0.f;
    const float SCALE = 0.125f * 1.44269504088896341f;   // (1/sqrt(64)) * log2(e)

    auto stage = [&](int kv0, int buf) {
        #pragma unroll
        for (int rr = 0; rr < 2; ++rr) {
            int r = (rr << 5) + rS;
            int cs = (cS ^ (r & 7)) << 3;
            gll16(Kbase + (size_t)(kv0 + r)*2048 + cs, &Kd[buf][((rr<<8) + tid)*8]);
            gll16(Vtg + ((size_t)r << 11) + kv0 + cs,  &Vs[buf][((rr<<8) + tid)*8]);
        }
    };

    auto tile_compute = [&](int cur) {
        // P^T = K Q^T  (per wave: 64 kv x 32 q); lane holds P[kv=16mf+4lh+v][q=16qf+l15]
        f32x4 p2[4][2] = {};
        #pragma unroll
        for (int ks = 0; ks < 2; ++ks)
            #pragma unroll
            for (int mf = 0; mf < 4; ++mf) {
                int r = (mf << 4) + l15;
                int cc = ((ks << 5) + (lh << 3)) ^ ((r & 7) << 3);
                bf16x8 kf = *(const bf16x8*)(&Kd[cur][r*64 + cc]);
                #pragma unroll
                for (int qf = 0; qf < 2; ++qf)
                    p2[mf][qf] = __builtin_amdgcn_mfma_f32_16x16x32_bf16(
                        kf, qfr[qf][ks], p2[mf][qf], 0, 0, 0);
            }

        // in-register online softmax (q = l15 lane-local), defer-max THR=8
        #pragma unroll
        for (int qf = 0; qf < 2; ++qf) {
            float ma = fmaxf(fmaxf(p2[0][qf][0], p2[0][qf][1]),
                             fmaxf(p2[0][qf][2], p2[0][qf][3]));
            float mb = fmaxf(fmaxf(p2[1][qf][0], p2[1][qf][1]),
                             fmaxf(p2[1][qf][2], p2[1][qf][3]));
            float mc = fmaxf(fmaxf(p2[2][qf][0], p2[2][qf][1]),
                             fmaxf(p2[2][qf][2], p2[2][qf][3]));
            float md = fmaxf(fmaxf(p2[3][qf][0], p2[3][qf][1]),
                             fmaxf(p2[3][qf][2], p2[3][qf][3]));
            float mt = fmaxf(fmaxf(ma, mb), fmaxf(mc, md));
            mt = fmaxf(mt, __shfl_xor(mt, 16));
            mt = fmaxf(mt, __shfl_xor(mt, 32));
            float mts = mt * SCALE;
            if (__any(mts > mr[qf] + 8.0f)) {      // T13: rescale only on real growth
                float mnew = fmaxf(mr[qf], mts);
                float alpha = exp2n(mr[qf] - mnew);
                mr[qf] = mnew;
                sr[qf] *= alpha;
                #pragma unroll
                for (int df = 0; df < 4; ++df)
                    #pragma unroll
                    for (int v = 0; v < 4; ++v)
                        o[qf][df][v] *= alpha;
            }
            float m_use = mr[qf];
            float tsp[4];
            #pragma unroll
            for (int mf = 0; mf < 4; ++mf) {
                #pragma unroll
                for (int v = 0; v < 4; ++v)
                    p2[mf][qf][v] = exp2n(p2[mf][qf][v] * SCALE - m_use);
                tsp[mf] = (p2[mf][qf][0] + p2[mf][qf][1]) +
                          (p2[mf][qf][2] + p2[mf][qf][3]);
            }
            float ts = (tsp[0] + tsp[1]) + (tsp[2] + tsp[3]);
            ts += __shfl_xor(ts, 16);
            ts += __shfl_xor(ts, 32);
            sr[qf] += ts;
            // write P[q][kv] to wave-private LDS via packed cvt
            int row = (qf << 4) + l15;
            int rs = (row & 7) << 3;
            #pragma unroll
            for (int mf = 0; mf < 4; ++mf) {
                i32x2 dw;
                dw[0] = cvtpk(p2[mf][qf][0], p2[mf][qf][1]);
                dw[1] = cvtpk(p2[mf][qf][2], p2[mf][qf][3]);
                *(i32x2*)(Plw + row*64 + (((mf << 4) + (lh << 2)) ^ rs)) = dw;
            }
        }

        // PV: O^T += V^T · P  (A = V^T rows d, B = P rows q; D[d][q])
        wait_lgkm0();
        bf16x8 pa[2][2];
        #pragma unroll
        for (int ks = 0; ks < 2; ++ks)
            #pragma unroll
            for (int qf = 0; qf < 2; ++qf) {
                int r = (qf << 4) + l15;
                int cc = ((ks << 5) + (lh << 3)) ^ ((r & 7) << 3);
                pa[ks][qf] = *(const bf16x8*)(Plw + r*64 + cc);
            }
        #pragma unroll
        for (int ks = 0; ks < 2; ++ks)
            #pragma unroll
            for (int df = 0; df < 4; ++df) {
                int r = (df << 4) + l15;
                int cc = ((ks << 5) + (lh << 3)) ^ ((r & 7) << 3);
                bf16x8 vb = *(const bf16x8*)(&Vs[cur][r*64 + cc]);
                #pragma unroll
                for (int qf = 0; qf < 2; ++qf)
                    o[qf][df] = __builtin_amdgcn_mfma_f32_16x16x32_bf16(
                        vb, pa[ks][qf], o[qf][df], 0, 0, 0);
            }
    };

    stage(0, 0);
    for (int it = 0; it < 31; ++it) {
        int cur = it & 1;
        stage((it + 1) << 6, cur ^ 1);   // issue next tile BEFORE computing current
        wait_vm4();                      // current tile's 4 loads (older) complete
        __syncthreads();                 // publish tile
        tile_compute(cur);
        __syncthreads();                 // protect buf before next-iter overwrite
    }
    wait_vm0();
    __syncthreads();
    tile_compute(1);                     // it=31

    // epilogue: O[q][d] = o^T / sr; q = l15, d = df*16 + lh*4 + v
    #pragma unroll
    for (int qf = 0; qf < 2; ++qf) {
        float inv = 1.0f / sr[qf];
        int t = qt0 + (w << 5) + (qf << 4) + l15;
        short* rowp = Ob + (size_t)((b << 11) + t) * 1024 + (h << 6);
        #pragma unroll
        for (int df = 0; df < 4; ++df) {
            s16x4 st;
            #pragma unroll
            for (int v = 0; v < 4; ++v)
                st[v] = f2bf(o[qf][df][v] * inv);
            *(s16x4*)(rowp + (df << 4) + (lh << 2)) = st;
        }
    }
}

extern "C" void kernel_launch(void* const* d_in, const int* in_sizes, int n_in,
                              void* d_out, int out_size, void* d_ws, size_t ws_size,
                              hipStream_t stream)
{
    const float* x     = (const float*)d_in[0];
    const float* w_qkv = (const float*)d_in[1];
    const float* b_qkv = (const float*)d_in[2];
    const float* w_out = (const float*)d_in[3];
    const float* b_out = (const float*)d_in[4];
    float* out = (float*)d_out;

    // workspace layout (bf16 shorts): qk | Vt | wqb | wob | xb(=Ob)
    short* qk  = (short*)d_ws;                       // 8192*2048
    short* Vt  = qk  + (size_t)8192*2048;            // 64*64*2048
    short* wqb = Vt  + (size_t)64*64*2048;           // 3072*1024
    short* wob = wqb + (size_t)3072*1024;            // 1024*1024
    short* xb  = wob + (size_t)1024*1024;            // 8192*1024 (reused as Ob)
    short* Ob  = xb;

    k_convert<<<2048, 256, 0, stream>>>(x, xb, w_qkv, wqb, w_out, wob);
    k_gemm<0><<<dim3(64, 24), 256, 0, stream>>>(xb, wqb, b_qkv, (void*)qk, (void*)Vt, 2048, 1024);
    k_attn<<<dim3(16, 64), 256, 0, stream>>>(qk, Vt, Ob);
    k_gemm<1><<<dim3(64, 8), 256, 0, stream>>>(Ob, wob, b_out, (void*)out, (void*)nullptr, 1024, 1024);
}

// Round 8
// 323.456 us; speedup vs baseline: 1.8725x; 1.0253x over previous
//
#include <hip/hip_runtime.h>
#include <stdint.h>

typedef __attribute__((ext_vector_type(8))) short bf16x8;
typedef __attribute__((ext_vector_type(4))) short s16x4;
typedef __attribute__((ext_vector_type(4))) float f32x4;
typedef __attribute__((ext_vector_type(2))) int i32x2;

#define DEV static __device__ __forceinline__

// (1/sqrt(64)) * log2(e) — folded into Q weights/bias so softmax needs no scale mul
#define SCALEQ (0.125f * 1.44269504088896341f)

DEV short f2bf(float f) {
    union { float f; uint32_t u; } v; v.f = f;
    uint32_t r = (v.u + 0x7fffu + ((v.u >> 16) & 1u)) >> 16;
    return (short)r;
}

DEV int cvtpk(float lo, float hi) {   // [15:0]=bf16(lo), [31:16]=bf16(hi), RNE
    int r;
    asm("v_cvt_pk_bf16_f32 %0, %1, %2" : "=v"(r) : "v"(lo), "v"(hi));
    return r;
}

DEV float exp2n(float x) { return __builtin_amdgcn_exp2f(x); }

DEV void gll16(const void* g, void* l) {
    __builtin_amdgcn_global_load_lds(
        (const __attribute__((address_space(1))) uint32_t*)g,
        (__attribute__((address_space(3))) uint32_t*)l, 16, 0, 0);
}

DEV void wait_vm0()   { asm volatile("s_waitcnt vmcnt(0)" ::: "memory"); }
DEV void wait_vm4()   { asm volatile("s_waitcnt vmcnt(4)" ::: "memory"); }
DEV void wait_lgkm0() { asm volatile("s_waitcnt lgkmcnt(0)" ::: "memory"); }

// ---------------- fp32 -> bf16 convert (Q-rows of w_qkv pre-scaled) ----------------
__global__ __launch_bounds__(256) void k_convert(
    const float* __restrict__ x,  short* __restrict__ xb,
    const float* __restrict__ wq, short* __restrict__ wqb,
    const float* __restrict__ wo, short* __restrict__ wob)
{
    const int NX = (8192*1024)/4, NW = (3072*1024)/4, NO = (1024*1024)/4;
    const int NQ = (1024*1024)/4;            // first 1024 rows of w_qkv = Q weights
    const int total = NX + NW + NO;
    for (int i = blockIdx.x*blockDim.x + threadIdx.x; i < total; i += gridDim.x*blockDim.x) {
        const float* s; short* d; int j; float fs = 1.0f;
        if (i < NX)           { s = x;  d = xb;  j = i; }
        else if (i < NX + NW) { s = wq; d = wqb; j = i - NX; if (j < NQ) fs = SCALEQ; }
        else                  { s = wo; d = wob; j = i - NX - NW; }
        f32x4 v = *(const f32x4*)(s + (size_t)j*4);
        s16x4 o;
        o[0] = f2bf(v[0]*fs); o[1] = f2bf(v[1]*fs); o[2] = f2bf(v[2]*fs); o[3] = f2bf(v[3]*fs);
        *(s16x4*)(d + (size_t)j*4) = o;
    }
}

// ---------------- NT GEMM: C[m][n] = sum_k A[m][k]*Bw[n][k] + bias[n] ----------------
// MODE 0 (QKV): n<2048 -> bf16 qk[8192][2048] (Q cols pre-scaled incl. bias);
//               n>=2048 -> V transposed into Vt[b*16+h][d][t].  MODE 1: fp32 direct.
template<int MODE>
__global__ __launch_bounds__(256) void k_gemm(
    const short* __restrict__ A,    // [Mtot][K] bf16
    const short* __restrict__ Bw,   // [Ntot][K] bf16
    const float* __restrict__ bias, // [Ntot] fp32
    void* __restrict__ Cout,        // MODE0: qk base; MODE1: fp32 out
    void* __restrict__ Cout2,       // MODE0: Vt base; MODE1: unused
    int Nld, int K)
{
    __shared__ short smem[17408];       // As[8192] | Bs[8192]; epilogue C[128][136]
    short* As = smem;
    short* Bs = smem + 8192;
    const int tid = threadIdx.x;
    const int l = tid & 63, w = tid >> 6;
    const int bm = blockIdx.x << 7, bn = blockIdx.y << 7;
    const int wm = (w >> 1) << 6, wn = (w & 1) << 6;
    const int l15 = l & 15, lh = l >> 4;
    const int rS = tid >> 3, cS = tid & 7;   // staging: row chunk within 32-row round

    f32x4 acc[4][4] = {};
    const int KT = K >> 6;

    for (int kt = 0; kt < KT; ++kt) {
        const int k0 = kt << 6;
        #pragma unroll
        for (int rr = 0; rr < 4; ++rr) {
            int r = (rr << 5) + rS;
            int cs = (cS ^ (r & 7)) << 3;            // pre-swizzled global source
            gll16(A  + (size_t)(bm + r)*K + k0 + cs, As + ((rr<<8) + tid)*8);
            gll16(Bw + (size_t)(bn + r)*K + k0 + cs, Bs + ((rr<<8) + tid)*8);
        }
        wait_vm0();
        __syncthreads();

        bf16x8 af[2][4], bfr[2][4];
        #pragma unroll
        for (int ks = 0; ks < 2; ++ks) {
            #pragma unroll
            for (int mf = 0; mf < 4; ++mf) {
                int r = wm + (mf << 4) + l15;
                int cc = ((ks << 5) + (lh << 3)) ^ ((r & 7) << 3);
                af[ks][mf] = *(const bf16x8*)(As + r*64 + cc);
            }
            #pragma unroll
            for (int nf = 0; nf < 4; ++nf) {
                int r = wn + (nf << 4) + l15;
                int cc = ((ks << 5) + (lh << 3)) ^ ((r & 7) << 3);
                bfr[ks][nf] = *(const bf16x8*)(Bs + r*64 + cc);
            }
        }
        #pragma unroll
        for (int ks = 0; ks < 2; ++ks)
            #pragma unroll
            for (int mf = 0; mf < 4; ++mf)
                #pragma unroll
                for (int nf = 0; nf < 4; ++nf)
                    acc[mf][nf] = __builtin_amdgcn_mfma_f32_16x16x32_bf16(
                        af[ks][mf], bfr[ks][nf], acc[mf][nf], 0, 0, 0);
        __syncthreads();
    }

    float bv[4];
    #pragma unroll
    for (int nf = 0; nf < 4; ++nf) bv[nf] = bias[bn + wn + (nf<<4) + l15];
    if (MODE == 0 && bn < 1024) {          // Q columns: bias picks up the folded scale
        #pragma unroll
        for (int nf = 0; nf < 4; ++nf) bv[nf] *= SCALEQ;
    }

    if (MODE == 0) {
        #pragma unroll
        for (int mf = 0; mf < 4; ++mf)
            #pragma unroll
            for (int nf = 0; nf < 4; ++nf)
                #pragma unroll
                for (int v = 0; v < 4; ++v) {
                    int r = wm + (mf<<4) + (lh<<2) + v;
                    int c = wn + (nf<<4) + l15;
                    smem[r*136 + c] = f2bf(acc[mf][nf][v] + bv[nf]);
                }
        __syncthreads();
        if (bn < 2048) {
            int r = tid >> 1, half = tid & 1;
            const short* src = smem + r*136 + (half << 6);
            short* dst = (short*)Cout + (size_t)(bm + r)*2048 + bn + (half << 6);
            #pragma unroll
            for (int c = 0; c < 8; ++c)
                *(bf16x8*)(dst + (c<<3)) = *(const bf16x8*)(src + (c<<3));
        } else {
            // transposed store of V columns: Vt[(b*16+h)][d][t]
            int nl = tid >> 1;                 // 0..127 (n within tile)
            int nloc = (bn - 2048) + nl;
            int hh = nloc >> 6, d = nloc & 63;
            int tl0 = (tid & 1) << 6;          // 0 or 64 (t within tile)
            int bb = bm >> 11;
            int tt0 = (bm & 2047) + tl0;
            short* dst = (short*)Cout2 + (((size_t)((bb << 4) + hh) << 6) + d) * 2048 + tt0;
            #pragma unroll
            for (int c = 0; c < 8; ++c) {
                bf16x8 pk;
                #pragma unroll
                for (int j = 0; j < 8; ++j)
                    pk[j] = smem[(tl0 + (c<<3) + j)*136 + nl];
                *(bf16x8*)(dst + (c<<3)) = pk;
            }
        }
    } else {
        float* C = (float*)Cout;
        #pragma unroll
        for (int mf = 0; mf < 4; ++mf)
            #pragma unroll
            for (int nf = 0; nf < 4; ++nf)
                #pragma unroll
                for (int v = 0; v < 4; ++v) {
                    int r = bm + wm + (mf<<4) + (lh<<2) + v;
                    int c = bn + wn + (nf<<4) + l15;
                    C[(size_t)r*Nld + c] = acc[mf][nf][v] + bv[nf];
                }
    }
}

// ---------------- flash attention (swapped QK^T, in-reg softmax, LDS P handoff) ----
// qk: [8192][2048] bf16 rows m=b*2048+t, cols: Q h*64+d (pre-scaled) | K 1024+h*64+d
// Vt: [64 bh][64 d][2048 t] bf16
// Ob: [8192][1024] bf16
__global__ __launch_bounds__(256) void k_attn(
    const short* __restrict__ qk, const short* __restrict__ Vt,
    short* __restrict__ Ob)
{
    __shared__ short Kd[2][4096];    // K tile  [64 kv][64 d]   (swizzled, dbuf)
    __shared__ short Vs[2][4096];    // V^T tile [64 d][64 kv]  (swizzled, dbuf)
    __shared__ short Pl[4][2048];    // per-wave P [32 q][64 kv] (swizzled)

    const int tid = threadIdx.x;
    const int l = tid & 63, w = tid >> 6;
    const int l15 = l & 15, lh = l >> 4;
    const int qt0 = blockIdx.x << 7;
    const int bh = blockIdx.y;
    const int b = bh >> 4, h = bh & 15;
    const short* Qbase = qk + (size_t)(b << 11) * 2048 + (h << 6);
    const short* Kbase = Qbase + 1024;
    const short* Vtg = Vt + ((size_t)bh << 17);    // 64*2048 per (b,h)
    short* Plw = &Pl[w][0];
    const int rS = tid >> 3, cS = tid & 7;

    // Q fragments in registers for the whole block lifetime
    bf16x8 qfr[2][2];
    #pragma unroll
    for (int qf = 0; qf < 2; ++qf)
        #pragma unroll
        for (int ks = 0; ks < 2; ++ks) {
            int t = qt0 + (w << 5) + (qf << 4) + l15;
            qfr[qf][ks] = *(const bf16x8*)(Qbase + (size_t)t*2048 + (ks << 5) + (lh << 3));
        }

    f32x4 o[2][4] = {};
    float mr[2], sr[2];
    mr[0] = mr[1] = -__builtin_inff();
    sr[0] = sr[1] = 0.f;

    auto stage = [&](int kv0, int buf) {
        #pragma unroll
        for (int rr = 0; rr < 2; ++rr) {
            int r = (rr << 5) + rS;
            int cs = (cS ^ (r & 7)) << 3;
            gll16(Kbase + (size_t)(kv0 + r)*2048 + cs, &Kd[buf][((rr<<8) + tid)*8]);
            gll16(Vtg + ((size_t)r << 11) + kv0 + cs,  &Vs[buf][((rr<<8) + tid)*8]);
        }
    };

    auto tile_compute = [&](int cur) {
        // P^T = K Q^T (already in exp2 units); lane holds P[kv=16mf+4lh+v][q=16qf+l15]
        f32x4 p2[4][2] = {};
        __builtin_amdgcn_s_setprio(1);
        #pragma unroll
        for (int ks = 0; ks < 2; ++ks)
            #pragma unroll
            for (int mf = 0; mf < 4; ++mf) {
                int r = (mf << 4) + l15;
                int cc = ((ks << 5) + (lh << 3)) ^ ((r & 7) << 3);
                bf16x8 kf = *(const bf16x8*)(&Kd[cur][r*64 + cc]);
                #pragma unroll
                for (int qf = 0; qf < 2; ++qf)
                    p2[mf][qf] = __builtin_amdgcn_mfma_f32_16x16x32_bf16(
                        kf, qfr[qf][ks], p2[mf][qf], 0, 0, 0);
            }
        __builtin_amdgcn_s_setprio(0);

        // in-register online softmax (q = l15 lane-local), defer-max THR=8
        #pragma unroll
        for (int qf = 0; qf < 2; ++qf) {
            float ma = fmaxf(fmaxf(p2[0][qf][0], p2[0][qf][1]),
                             fmaxf(p2[0][qf][2], p2[0][qf][3]));
            float mb = fmaxf(fmaxf(p2[1][qf][0], p2[1][qf][1]),
                             fmaxf(p2[1][qf][2], p2[1][qf][3]));
            float mc = fmaxf(fmaxf(p2[2][qf][0], p2[2][qf][1]),
                             fmaxf(p2[2][qf][2], p2[2][qf][3]));
            float md = fmaxf(fmaxf(p2[3][qf][0], p2[3][qf][1]),
                             fmaxf(p2[3][qf][2], p2[3][qf][3]));
            float mt = fmaxf(fmaxf(ma, mb), fmaxf(mc, md));
            mt = fmaxf(mt, __shfl_xor(mt, 16));
            mt = fmaxf(mt, __shfl_xor(mt, 32));
            if (__any(mt > mr[qf] + 8.0f)) {      // T13: rescale only on real growth
                float mnew = fmaxf(mr[qf], mt);
                float alpha = exp2n(mr[qf] - mnew);
                mr[qf] = mnew;
                sr[qf] *= alpha;
                #pragma unroll
                for (int df = 0; df < 4; ++df)
                    #pragma unroll
                    for (int v = 0; v < 4; ++v)
                        o[qf][df][v] *= alpha;
            }
            float m_use = mr[qf];
            float tsp[4];
            #pragma unroll
            for (int mf = 0; mf < 4; ++mf) {
                #pragma unroll
                for (int v = 0; v < 4; ++v)
                    p2[mf][qf][v] = exp2n(p2[mf][qf][v] - m_use);
                tsp[mf] = (p2[mf][qf][0] + p2[mf][qf][1]) +
                          (p2[mf][qf][2] + p2[mf][qf][3]);
            }
            float ts = (tsp[0] + tsp[1]) + (tsp[2] + tsp[3]);
            ts += __shfl_xor(ts, 16);
            ts += __shfl_xor(ts, 32);
            sr[qf] += ts;
            // write P[q][kv] to wave-private LDS via packed cvt
            int row = (qf << 4) + l15;
            int rs = (row & 7) << 3;
            #pragma unroll
            for (int mf = 0; mf < 4; ++mf) {
                i32x2 dw;
                dw[0] = cvtpk(p2[mf][qf][0], p2[mf][qf][1]);
                dw[1] = cvtpk(p2[mf][qf][2], p2[mf][qf][3]);
                *(i32x2*)(Plw + row*64 + (((mf << 4) + (lh << 2)) ^ rs)) = dw;
            }
        }

        // PV: O^T += V^T · P  (A = V^T rows d, B = P rows q; D[d][q])
        wait_lgkm0();
        bf16x8 pa[2][2];
        #pragma unroll
        for (int ks = 0; ks < 2; ++ks)
            #pragma unroll
            for (int qf = 0; qf < 2; ++qf) {
                int r = (qf << 4) + l15;
                int cc = ((ks << 5) + (lh << 3)) ^ ((r & 7) << 3);
                pa[ks][qf] = *(const bf16x8*)(Plw + r*64 + cc);
            }
        __builtin_amdgcn_s_setprio(1);
        #pragma unroll
        for (int ks = 0; ks < 2; ++ks)
            #pragma unroll
            for (int df = 0; df < 4; ++df) {
                int r = (df << 4) + l15;
                int cc = ((ks << 5) + (lh << 3)) ^ ((r & 7) << 3);
                bf16x8 vb = *(const bf16x8*)(&Vs[cur][r*64 + cc]);
                #pragma unroll
                for (int qf = 0; qf < 2; ++qf)
                    o[qf][df] = __builtin_amdgcn_mfma_f32_16x16x32_bf16(
                        vb, pa[ks][qf], o[qf][df], 0, 0, 0);
            }
        __builtin_amdgcn_s_setprio(0);
    };

    stage(0, 0);
    for (int it = 0; it < 31; ++it) {
        int cur = it & 1;
        stage((it + 1) << 6, cur ^ 1);   // issue next tile BEFORE computing current
        wait_vm4();                      // current tile's 4 loads (older) complete
        __syncthreads();                 // publish tile
        tile_compute(cur);
        __syncthreads();                 // protect buf before next-iter overwrite
    }
    wait_vm0();
    __syncthreads();
    tile_compute(1);                     // it=31

    // epilogue: O[q][d] = o^T / sr; q = l15, d = df*16 + lh*4 + v
    #pragma unroll
    for (int qf = 0; qf < 2; ++qf) {
        float inv = 1.0f / sr[qf];
        int t = qt0 + (w << 5) + (qf << 4) + l15;
        short* rowp = Ob + (size_t)((b << 11) + t) * 1024 + (h << 6);
        #pragma unroll
        for (int df = 0; df < 4; ++df) {
            s16x4 st;
            #pragma unroll
            for (int v = 0; v < 4; ++v)
                st[v] = f2bf(o[qf][df][v] * inv);
            *(s16x4*)(rowp + (df << 4) + (lh << 2)) = st;
        }
    }
}

extern "C" void kernel_launch(void* const* d_in, const int* in_sizes, int n_in,
                              void* d_out, int out_size, void* d_ws, size_t ws_size,
                              hipStream_t stream)
{
    const float* x     = (const float*)d_in[0];
    const float* w_qkv = (const float*)d_in[1];
    const float* b_qkv = (const float*)d_in[2];
    const float* w_out = (const float*)d_in[3];
    const float* b_out = (const float*)d_in[4];
    float* out = (float*)d_out;

    // workspace layout (bf16 shorts): qk | Vt | wqb | wob | xb(=Ob)
    short* qk  = (short*)d_ws;                       // 8192*2048
    short* Vt  = qk  + (size_t)8192*2048;            // 64*64*2048
    short* wqb = Vt  + (size_t)64*64*2048;           // 3072*1024
    short* wob = wqb + (size_t)3072*1024;            // 1024*1024
    short* xb  = wob + (size_t)1024*1024;            // 8192*1024 (reused as Ob)
    short* Ob  = xb;

    k_convert<<<2048, 256, 0, stream>>>(x, xb, w_qkv, wqb, w_out, wob);
    k_gemm<0><<<dim3(64, 24), 256, 0, stream>>>(xb, wqb, b_qkv, (void*)qk, (void*)Vt, 2048, 1024);
    k_attn<<<dim3(16, 64), 256, 0, stream>>>(qk, Vt, Ob);
    k_gemm<1><<<dim3(64, 8), 256, 0, stream>>>(Ob, wob, b_out, (void*)out, (void*)nullptr, 1024, 1024);
}